// Round 15
// baseline (230.754 us; speedup 1.0000x reference)
//
#include <hip/hip_runtime.h>

#define N_DRUG 572
#define EMB    256
#define K_NB   128
#define N_EDGE 4576
#define BN_EPS 1e-5f

// ---- K1: scores (all 128, redundant per chunk) + softmax + gather chunk ----
// grid = N_DRUG*4 blocks; block (b,c) gathers neighbors c*32..c*32+31 of drug b
__global__ __launch_bounds__(256) void sg_kernel(
    const int* __restrict__ drug_name,
    const int* __restrict__ adj_tail,
    const int* __restrict__ adj_relation,
    const float* __restrict__ drug_table,
    const float* __restrict__ rela_table,
    const float* __restrict__ ent_table,
    float* __restrict__ att4)          // [N_DRUG*4, EMB] per-chunk partials
{
    __shared__ float sc[K_NB];
    __shared__ float wred[2];
    __shared__ float part[4][EMB];

    const int b    = blockIdx.x >> 2;
    const int c    = blockIdx.x & 3;
    const int tid  = threadIdx.x;
    const int lane = tid & 63;
    const int wv   = tid >> 6;

    const float4 dv =
        ((const float4*)(drug_table + (size_t)drug_name[b] * EMB))[lane];

    // all 128 scores: wave wv owns k = wv*32 .. wv*32+31, 4 batches of 8
    #pragma unroll
    for (int batch = 0; batch < 4; ++batch) {
        const int kb = wv * 32 + batch * 8;
        float p[8];
        #pragma unroll
        for (int j = 0; j < 8; ++j) {
            const int rel = adj_relation[b * K_NB + kb + j];
            const float4 rv =
                ((const float4*)(rela_table + (size_t)rel * EMB))[lane];
            p[j] = dv.x * rv.x + dv.y * rv.y + dv.z * rv.z + dv.w * rv.w;
        }
        #pragma unroll
        for (int j = 0; j < 8; ++j) {
            float s = p[j];
            #pragma unroll
            for (int off = 32; off; off >>= 1) s += __shfl_xor(s, off, 64);
            if (lane == 0) sc[kb + j] = s;
        }
    }
    __syncthreads();

    // softmax over sc[0..127] (threads 0..127 active in reduces)
    float pv = 0.f;
    if (tid < K_NB) {
        float m = sc[tid];
        #pragma unroll
        for (int off = 32; off; off >>= 1)
            m = fmaxf(m, __shfl_xor(m, off, 64));
        if (lane == 0) wred[wv] = m;
    }
    __syncthreads();
    const float gmax = fmaxf(wred[0], wred[1]);
    __syncthreads();
    if (tid < K_NB) {
        pv = __expf(sc[tid] - gmax);
        float s = pv;
        #pragma unroll
        for (int off = 32; off; off >>= 1) s += __shfl_xor(s, off, 64);
        if (lane == 0) wred[wv] = s;
    }
    __syncthreads();
    if (tid < K_NB) sc[tid] = pv / (wred[0] + wred[1]);
    __syncthreads();

    // gather this block's chunk: wave wv handles 8 neighbors, unrolled
    const int kb2 = c * 32 + wv * 8;
    float4 acc = make_float4(0.f, 0.f, 0.f, 0.f);
    #pragma unroll
    for (int j = 0; j < 8; ++j) {
        const int k = kb2 + j;
        const float a = sc[k];
        const int   t = adj_tail[b * K_NB + k];
        const float4 ev = ((const float4*)(ent_table + (size_t)t * EMB))[lane];
        acc.x = fmaf(a, ev.x, acc.x);
        acc.y = fmaf(a, ev.y, acc.y);
        acc.z = fmaf(a, ev.z, acc.z);
        acc.w = fmaf(a, ev.w, acc.w);
    }
    ((float4*)part[wv])[lane] = acc;
    __syncthreads();
    // slice write — no atomics, no zero-init needed
    att4[(size_t)blockIdx.x * EMB + tid] =
        part[0][tid] + part[1][tid] + part[2][tid] + part[3][tid];
}

// ---- K2: Linear(2E->E) split-K + ReLU + BN-stat atomics ----
__global__ __launch_bounds__(512) void linear_kernel(
    const int* __restrict__ drug_name,
    const float* __restrict__ att4,
    const float* __restrict__ drug_table,
    const float* __restrict__ lin_W,
    const float* __restrict__ lin_b,
    float* __restrict__ h,
    float* __restrict__ s1,
    float* __restrict__ s2)
{
    __shared__ float xs[2 * EMB];
    __shared__ float part[2][EMB];

    const int b   = blockIdx.x;
    const int tid = threadIdx.x;

    if (tid < EMB) {
        const float* a0 = att4 + (size_t)(b * 4) * EMB;
        xs[tid] = a0[tid] + a0[EMB + tid] + a0[2 * EMB + tid] + a0[3 * EMB + tid];
    } else {
        xs[tid] = drug_table[(size_t)drug_name[b] * EMB + (tid - EMB)];
    }
    __syncthreads();

    const int col  = tid & (EMB - 1);
    const int half = tid >> 8;
    const float* wp = lin_W + (size_t)(half * EMB) * EMB + col;
    const float* xp = xs + half * EMB;
    float acc = 0.f;
    #pragma unroll 16
    for (int i = 0; i < EMB; ++i)
        acc = fmaf(xp[i], wp[(size_t)i * EMB], acc);
    part[half][col] = acc;
    __syncthreads();

    if (tid < EMB) {
        const float v = fmaxf(part[0][tid] + part[1][tid] + lin_b[tid], 0.f);
        h[(size_t)b * EMB + tid] = v;
        atomicAdd(&s1[tid], v);
        atomicAdd(&s2[tid], v * v);
    }
}

// ---- K3: edge scatter with inline BN — 2 edges per block ----
#define EPB 2
__global__ __launch_bounds__(256) void scatter_bn(
    const int* __restrict__ nb_src, const int* __restrict__ nb_dst,
    const int* __restrict__ epoch,
    const float* __restrict__ h,
    const float* __restrict__ s1, const float* __restrict__ s2,
    const float* __restrict__ gamma, const float* __restrict__ beta,
    float* __restrict__ nb_sum,
    float* __restrict__ cnt)
{
    if (*epoch <= 1) return;
    const int tid = threadIdx.x;
    const float invN  = 1.0f / (float)N_DRUG;
    const float mean  = s1[tid] * invN;
    const float var   = s2[tid] * invN - mean * mean;
    const float scale = gamma[tid] * rsqrtf(var + BN_EPS);
    const float bet   = beta[tid];

    const int e0 = blockIdx.x * EPB;
    #pragma unroll
    for (int e = e0; e < e0 + EPB; ++e) {
        const int s = nb_src[e];
        const int d = nb_dst[e];
        const float f = (h[(size_t)s * EMB + tid] - mean) * scale + bet;
        atomicAdd(&nb_sum[(size_t)d * EMB + tid], f);
        if (tid == 0) atomicAdd(&cnt[d], 1.0f);
    }
}

// ---- K4: combine with inline BN -> out ----
__global__ __launch_bounds__(256) void combine_bn(
    const float* __restrict__ h,
    const float* __restrict__ s1, const float* __restrict__ s2,
    const float* __restrict__ gamma, const float* __restrict__ beta,
    const float* __restrict__ nb_sum,
    const float* __restrict__ cnt,
    const int* __restrict__ epoch,
    float* __restrict__ out)
{
    const int b   = blockIdx.x;
    const int tid = threadIdx.x;
    const size_t idx = (size_t)b * EMB + tid;
    const float invN  = 1.0f / (float)N_DRUG;
    const float mean  = s1[tid] * invN;
    const float var   = s2[tid] * invN - mean * mean;
    const float scale = gamma[tid] * rsqrtf(var + BN_EPS);
    float f = (h[idx] - mean) * scale + beta[tid];
    if (*epoch > 1) {
        const float c = cnt[b];
        if (c > 0.f) f = (nb_sum[idx] / c + f) * 0.5f;
    }
    out[idx] = f;
}

extern "C" void kernel_launch(void* const* d_in, const int* in_sizes, int n_in,
                              void* d_out, int out_size, void* d_ws, size_t ws_size,
                              hipStream_t stream) {
    const int*   drug_name    = (const int*)d_in[0];
    const int*   adj_tail     = (const int*)d_in[1];
    const int*   adj_relation = (const int*)d_in[2];
    const int*   nb_src       = (const int*)d_in[3];
    const int*   nb_dst       = (const int*)d_in[4];
    const int*   epoch        = (const int*)d_in[5];
    const float* drug_table   = (const float*)d_in[6];
    const float* rela_table   = (const float*)d_in[7];
    const float* ent_table    = (const float*)d_in[8];
    const float* lin_W        = (const float*)d_in[9];
    const float* lin_b        = (const float*)d_in[10];
    const float* bn_gamma     = (const float*)d_in[11];
    const float* bn_beta      = (const float*)d_in[12];
    float* out = (float*)d_out;

    // ws layout (floats): h | [zero region: s1 s2 cnt nb_sum] | att4
    float* ws = (float*)d_ws;
    float* h      = ws;                    // 572*256
    float* s1     = h + N_DRUG * EMB;      // 256   (zero-region base)
    float* s2     = s1 + EMB;              // 256
    float* cnt    = s2 + EMB;              // 572
    float* nb_sum = cnt + N_DRUG;          // 572*256
    float* att4   = nb_sum + N_DRUG * EMB; // 572*4*256
    const size_t zero_bytes =
        (size_t)(EMB + EMB + N_DRUG + N_DRUG * EMB) * sizeof(float);

    hipMemsetAsync(s1, 0, zero_bytes, stream);

    sg_kernel<<<N_DRUG * 4, 256, 0, stream>>>(drug_name, adj_tail, adj_relation,
                                              drug_table, rela_table, ent_table,
                                              att4);

    linear_kernel<<<N_DRUG, 512, 0, stream>>>(drug_name, att4, drug_table,
                                              lin_W, lin_b, h, s1, s2);

    scatter_bn<<<N_EDGE / EPB, 256, 0, stream>>>(nb_src, nb_dst, epoch,
                                                 h, s1, s2, bn_gamma, bn_beta,
                                                 nb_sum, cnt);

    combine_bn<<<N_DRUG, 256, 0, stream>>>(h, s1, s2, bn_gamma, bn_beta,
                                           nb_sum, cnt, epoch, out);
}